// Round 7
// baseline (128.445 us; speedup 1.0000x reference)
//
#include <hip/hip_runtime.h>

// 256 independent LSAP problems (scipy-trajectory-exact Jonker-Volgenant),
// one wave per problem, lane j owns column j and row j's dual state.
// FAST path (on-grid f32 inputs, i.e. exact multiples of 2^-23): entire solver
// runs in int32 scaled by 2^23 (exact order embedding -> identical trajectory),
// with the cost column held in VGPRs (4x i32x16, asm-opaque so the compiler
// cannot fold the uniform-index extract back into an LDS load -> v_movrels).
// Fallback: verified f64/LDS path (round 3). Output identical to reference.

typedef int i32x16 __attribute__((ext_vector_type(16)));

union DU { double d; int i2[2]; };

__device__ inline double readlane_f64(double x, int l) {
    DU a; a.d = x;
    DU o;
    o.i2[0] = __builtin_amdgcn_readlane(a.i2[0], l);
    o.i2[1] = __builtin_amdgcn_readlane(a.i2[1], l);
    return o.d;
}

template <int CTRL>
__device__ inline double dpp_min_f64(double x) {
    DU a; a.d = x;
    DU b;
    b.i2[0] = __builtin_amdgcn_update_dpp(0, a.i2[0], CTRL, 0xF, 0xF, true);
    b.i2[1] = __builtin_amdgcn_update_dpp(0, a.i2[1], CTRL, 0xF, 0xF, true);
    return fmin(x, b.d);
}

template <int CTRL>
__device__ inline int dpp_min_i32(int x) {
    const int o = __builtin_amdgcn_update_dpp(0, x, CTRL, 0xF, 0xF, true);
    return o < x ? o : x;
}

// ---------------- FAST path: int32-scaled, register-resident cost ----------
__device__ void run_lsap_i32(const i32x16& c0, const i32x16& c1,
                             const i32x16& c2, const i32x16& c3,
                             int lane, int c,
                             int& path_r, int& row4col_r, int& col4row_r)
{
    int u_s = 0;              // u[lane] * 2^23   (lane as row)
    int v_s = 0;              // v[lane] * 2^23   (lane as col)

    for (int cur_row = 0; cur_row < c; ++cur_row) {
        int  minv_s    = 0x7FFFFFFF;   // shortest path cost to column `lane`
        bool remaining = true;
        unsigned long long SR = 0ULL;
        int  i       = cur_row;        // wave-uniform
        int  min_val = 0;
        int  sink    = -1;

        while (sink < 0) {
            SR |= 1ULL << i;
            const int u_i = __builtin_amdgcn_readlane(u_s, i);
            const int iu  = __builtin_amdgcn_readfirstlane(i);
            int cv;
            if (iu < 32) cv = (iu < 16) ? c0[iu & 15] : c1[iu & 15];
            else         cv = (iu < 48) ? c2[iu & 15] : c3[iu & 15];
            // exact integer arithmetic: order-insensitive
            const int r = (cv - v_s) + (min_val - u_i);
            const bool upd = remaining && (r < minv_s);
            minv_s = upd ? r : minv_s;
            path_r = upd ? i : path_r;

            const int key = remaining ? minv_s : 0x7FFFFFFF;
            int k = dpp_min_i32<0xB1>(key);     // xor 1
            k = dpp_min_i32<0x4E>(k);           // xor 2
            k = dpp_min_i32<0x141>(k);          // ROW_HALF_MIRROR (xor 4)
            k = dpp_min_i32<0x140>(k);          // ROW_MIRROR      (xor 8)
            const int m0 = __builtin_amdgcn_readlane(k, 0);
            const int m1 = __builtin_amdgcn_readlane(k, 16);
            const int m2 = __builtin_amdgcn_readlane(k, 32);
            const int m3 = __builtin_amdgcn_readlane(k, 48);
            const int ma = m0 < m1 ? m0 : m1;
            const int mb = m2 < m3 ? m2 : m3;
            const int gmin = ma < mb ? ma : mb;

            const unsigned long long eq = __ballot(key == gmin);
            const int jsel = __ffsll(eq) - 1;   // lowest lane = np.argmin tie-break
            min_val   = gmin;
            remaining = remaining && (lane != jsel);
            const int rj = __builtin_amdgcn_readlane(row4col_r, jsel);
            if (rj < 0) sink = jsel; else i = rj;
        }

        // ---- dual updates (reference formulas, pre-augment col4row) ----
        {
            const bool scanned_row = (SR >> lane) & 1ULL;
            const int  gidx = col4row_r & 63;           // clamp -1 -> unused
            const int  mv_g = __shfl(minv_s, gidx, 64); // minv[col4row[lane]]
            if (lane == cur_row)       u_s += min_val;
            else if (scanned_row)      u_s += min_val - mv_g;
            if (!remaining)            v_s -= min_val - minv_s;  // scanned cols
        }

        // ---- augment along alternating path (predicated lane writes) ----
        {
            int jj = sink;
            while (true) {
                const int ii = __builtin_amdgcn_readlane(path_r, jj);
                if (lane == jj) row4col_r = ii;
                const int tmp = __builtin_amdgcn_readlane(col4row_r, ii);
                if (lane == ii) col4row_r = jj;
                jj = tmp;
                if (ii == cur_row) break;
            }
        }
    }
}

// ---------------- fallback: verified round-3 f64 / LDS path ----------------
__device__ void run_lsap_f64(const float* __restrict__ costL, int lane, int c,
                             int& path_r, int& row4col_r, int& col4row_r)
{
    const double INF = __builtin_inf();
    double u_d = 0.0, v_d = 0.0;

    for (int cur_row = 0; cur_row < c; ++cur_row) {
        double minv_d    = INF;
        bool   remaining = true;
        unsigned long long SR = 0ULL;
        int    i       = cur_row;
        double min_val = 0.0;
        int    sink    = -1;

        while (sink < 0) {
            SR |= 1ULL << i;
            const double u_i = readlane_f64(u_d, i);
            const float  cf  = costL[i * 64 + lane];
            double r = min_val + (double)cf;   // numpy order, no FMA
            r = r - u_i;
            r = r - v_d;
            const bool upd = remaining && (r < minv_d);
            minv_d = upd ? r : minv_d;
            path_r = upd ? i : path_r;

            const double key = remaining ? minv_d : INF;
            double k = dpp_min_f64<0xB1>(key);
            k = dpp_min_f64<0x4E>(k);
            k = dpp_min_f64<0x141>(k);
            k = dpp_min_f64<0x140>(k);
            const double m0 = readlane_f64(k, 0);
            const double m1 = readlane_f64(k, 16);
            const double m2 = readlane_f64(k, 32);
            const double m3 = readlane_f64(k, 48);
            const double kmin = fmin(fmin(m0, m1), fmin(m2, m3));
            const unsigned long long eq = __ballot(key == kmin);
            const int jsel = __ffsll(eq) - 1;
            min_val = kmin;
            remaining = remaining && (lane != jsel);
            const int rj = __builtin_amdgcn_readlane(row4col_r, jsel);
            if (rj < 0) sink = jsel; else i = rj;
        }

        {
            const bool scanned_row = (SR >> lane) & 1ULL;
            const int  gidx = col4row_r & 63;
            const double mv_g = __shfl(minv_d, gidx, 64);
            if (lane == cur_row)       u_d += min_val;
            else if (scanned_row)      u_d += min_val - mv_g;
            if (!remaining)            v_d -= min_val - minv_d;
        }
        {
            int jj = sink;
            while (true) {
                const int ii = __builtin_amdgcn_readlane(path_r, jj);
                if (lane == jj) row4col_r = ii;
                const int tmp = __builtin_amdgcn_readlane(col4row_r, ii);
                if (lane == ii) col4row_r = jj;
                jj = tmp;
                if (ii == cur_row) break;
            }
        }
    }
}

__global__ __launch_bounds__(64)
void lsap_solve(const float* __restrict__ cost,
                const float* __restrict__ gt,
                float* __restrict__ out,
                double* __restrict__ partial)
{
    const int b    = blockIdx.x;
    const int lane = threadIdx.x;          // column index (and row index for u)

    __shared__ float costL[64 * 64];       // row-major [row][col]
    __shared__ int   ordL[64];

    // ---- stage cost matrix to LDS (coalesced float4) ----
    const float4* cb4 = (const float4*)(cost + (size_t)b * 4096);
    float4*       cl4 = (float4*)costL;
#pragma unroll
    for (int i = 0; i < 16; ++i)
        cl4[i * 64 + lane] = cb4[i * 64 + lane];

    // ---- valid-box count: first all-zero [2,3] box ----
    const float* gb = gt + (size_t)b * 384 + lane * 6;
    bool iszero = true;
#pragma unroll
    for (int k = 0; k < 6; ++k) iszero = iszero && (gb[k] == 0.0f);
    unsigned long long zmask = __ballot(iszero);
    const int c = zmask ? (__ffsll(zmask) - 1) : 64;

    __syncthreads();           // costL visible

    // ---- column -> scaled-int registers + on-grid check ----
    // ci*[k] = cost[row][lane] * 2^23 exactly, rows split 0-15/16-31/32-47/48-63
    i32x16 c0, c1, c2, c3;
    bool ongrid = true;
#pragma unroll
    for (int k = 0; k < 16; ++k) {
        const double h0 = (double)costL[(k     ) * 64 + lane] * 8388608.0;
        const double h1 = (double)costL[(k + 16) * 64 + lane] * 8388608.0;
        const double h2 = (double)costL[(k + 32) * 64 + lane] * 8388608.0;
        const double h3 = (double)costL[(k + 48) * 64 + lane] * 8388608.0;
        ongrid = ongrid && (h0 >= 0.0) && (h0 < 16777216.0) && (h0 == floor(h0))
                        && (h1 >= 0.0) && (h1 < 16777216.0) && (h1 == floor(h1))
                        && (h2 >= 0.0) && (h2 < 16777216.0) && (h2 == floor(h2))
                        && (h3 >= 0.0) && (h3 < 16777216.0) && (h3 == floor(h3));
        c0[k] = (int)h0; c1[k] = (int)h1; c2[k] = (int)h2; c3[k] = (int)h3;
    }
    const bool fast = (__ballot(ongrid) == ~0ULL);

    // opacity barrier: values now live in VGPRs; extracts can't re-fold to LDS
    asm volatile("" : "+v"(c0), "+v"(c1), "+v"(c2), "+v"(c3));

    int path_r    = -1;        // path[lane]    (lane as col)
    int row4col_r = -1;        // row4col[lane] (lane as col)
    int col4row_r = -1;        // col4row[lane] (lane as row)

    if (fast) run_lsap_i32(c0, c1, c2, c3, lane, c, path_r, row4col_r, col4row_r);
    else      run_lsap_f64(costL, lane, c, path_r, row4col_r, col4row_r);

    // ---- ordering = concat(col4row[0:c], sorted unassigned columns) ----
    const bool assigned = (row4col_r >= 0);                 // lane as col
    const unsigned long long amask = __ballot(assigned);
    if (lane < c) ordL[lane] = col4row_r;                   // lane as row
    if (!assigned) {
        const unsigned long long below = (~amask) & ((1ULL << lane) - 1ULL);
        ordL[c + __popcll(below)] = lane;
    }
    __syncthreads();

    const int oc = ordL[lane];
    out[b * 64 + lane] = (float)oc;

    // ---- per-block loss partial: sum_r cost[r, ordering[r]] ----
    double p = (double)costL[lane * 64 + oc];
#pragma unroll
    for (int s = 1; s < 64; s <<= 1) p += __shfl_xor(p, s, 64);
    if (lane == 0) partial[b] = p;
}

__global__ __launch_bounds__(256)
void loss_reduce(const double* __restrict__ partial, float* __restrict__ out,
                 int B)
{
    const int t = threadIdx.x;
    __shared__ double sb[4];
    double p = 0.0;
    for (int idx = t; idx < B; idx += 256) p += partial[idx];
#pragma unroll
    for (int s = 1; s < 64; s <<= 1) p += __shfl_xor(p, s, 64);
    if ((t & 63) == 0) sb[t >> 6] = p;
    __syncthreads();
    if (t == 0)
        out[B * 64] = (float)((sb[0] + sb[1] + sb[2] + sb[3]) / (double)(B * 64));
}

extern "C" void kernel_launch(void* const* d_in, const int* in_sizes, int n_in,
                              void* d_out, int out_size, void* d_ws, size_t ws_size,
                              hipStream_t stream)
{
    const float* cost = (const float*)d_in[0];   // [B,64,64] f32
    const float* gt   = (const float*)d_in[1];   // [B,64,2,3] f32
    float* out        = (float*)d_out;           // [B*64] ordering + [1] loss
    double* partial   = (double*)d_ws;           // B doubles of scratch

    const int B = in_sizes[0] / 4096;            // 64*64 per problem

    lsap_solve<<<B, 64, 0, stream>>>(cost, gt, out, partial);
    loss_reduce<<<1, 256, 0, stream>>>(partial, out, B);
}

// Round 8
// 102.025 us; speedup vs baseline: 1.2589x; 1.2589x over previous
//
#include <hip/hip_runtime.h>

// 256 independent LSAP problems (scipy-trajectory-exact Jonker-Volgenant),
// one wave per problem, lane j owns column j and row j's dual state.
// FAST path (on-grid f32 inputs = exact multiples of 2^-23): solver runs in
// int32 scaled by 2^23 (exact order embedding -> identical trajectory).
// Cost column lives in two i32x32 SSA vectors (VReg_1024); the per-scan read
// is extractelement with a readfirstlane'd (uniform) index -> v_movrels_b32.
// NO function boundary / reference on the vectors (that allocas them to
// scratch -- round-7 lesson). Fallback: verified f64/LDS path (round 3).

typedef int i32x32 __attribute__((ext_vector_type(32)));

union DU { double d; int i2[2]; };

__device__ inline double readlane_f64(double x, int l) {
    DU a; a.d = x;
    DU o;
    o.i2[0] = __builtin_amdgcn_readlane(a.i2[0], l);
    o.i2[1] = __builtin_amdgcn_readlane(a.i2[1], l);
    return o.d;
}

template <int CTRL>
__device__ inline double dpp_min_f64(double x) {
    DU a; a.d = x;
    DU b;
    b.i2[0] = __builtin_amdgcn_update_dpp(0, a.i2[0], CTRL, 0xF, 0xF, true);
    b.i2[1] = __builtin_amdgcn_update_dpp(0, a.i2[1], CTRL, 0xF, 0xF, true);
    return fmin(x, b.d);
}

template <int CTRL>
__device__ inline int dpp_min_i32(int x) {
    const int o = __builtin_amdgcn_update_dpp(0, x, CTRL, 0xF, 0xF, true);
    return o < x ? o : x;
}

// ---------------- fallback: verified round-3 f64 / LDS path ----------------
__device__ void run_lsap_f64(const float* __restrict__ costL, int lane, int c,
                             int& path_r, int& row4col_r, int& col4row_r)
{
    const double INF = __builtin_inf();
    double u_d = 0.0, v_d = 0.0;

    for (int cur_row = 0; cur_row < c; ++cur_row) {
        double minv_d    = INF;
        bool   remaining = true;
        unsigned long long SR = 0ULL;
        int    i       = cur_row;
        double min_val = 0.0;
        int    sink    = -1;

        while (sink < 0) {
            SR |= 1ULL << i;
            const double u_i = readlane_f64(u_d, i);
            const float  cf  = costL[i * 64 + lane];
            double r = min_val + (double)cf;   // numpy order, no FMA
            r = r - u_i;
            r = r - v_d;
            const bool upd = remaining && (r < minv_d);
            minv_d = upd ? r : minv_d;
            path_r = upd ? i : path_r;

            const double key = remaining ? minv_d : INF;
            double k = dpp_min_f64<0xB1>(key);
            k = dpp_min_f64<0x4E>(k);
            k = dpp_min_f64<0x141>(k);
            k = dpp_min_f64<0x140>(k);
            const double m0 = readlane_f64(k, 0);
            const double m1 = readlane_f64(k, 16);
            const double m2 = readlane_f64(k, 32);
            const double m3 = readlane_f64(k, 48);
            const double kmin = fmin(fmin(m0, m1), fmin(m2, m3));
            const unsigned long long eq = __ballot(key == kmin);
            const int jsel = __ffsll(eq) - 1;
            min_val = kmin;
            remaining = remaining && (lane != jsel);
            const int rj = __builtin_amdgcn_readlane(row4col_r, jsel);
            if (rj < 0) sink = jsel; else i = rj;
        }

        {
            const bool scanned_row = (SR >> lane) & 1ULL;
            const int  gidx = col4row_r & 63;
            const double mv_g = __shfl(minv_d, gidx, 64);
            if (lane == cur_row)       u_d += min_val;
            else if (scanned_row)      u_d += min_val - mv_g;
            if (!remaining)            v_d -= min_val - minv_d;
        }
        {
            int jj = sink;
            while (true) {
                const int ii = __builtin_amdgcn_readlane(path_r, jj);
                if (lane == jj) row4col_r = ii;
                const int tmp = __builtin_amdgcn_readlane(col4row_r, ii);
                if (lane == ii) col4row_r = jj;
                jj = tmp;
                if (ii == cur_row) break;
            }
        }
    }
}

__global__ __launch_bounds__(64)
void lsap_solve(const float* __restrict__ cost,
                const float* __restrict__ gt,
                float* __restrict__ out,
                double* __restrict__ partial)
{
    const int b    = blockIdx.x;
    const int lane = threadIdx.x;          // column index (and row index for u)

    __shared__ float costL[64 * 64];       // row-major [row][col]
    __shared__ int   ordL[64];

    // ---- stage cost matrix to LDS (coalesced float4) ----
    const float4* cb4 = (const float4*)(cost + (size_t)b * 4096);
    float4*       cl4 = (float4*)costL;
#pragma unroll
    for (int i = 0; i < 16; ++i)
        cl4[i * 64 + lane] = cb4[i * 64 + lane];

    // ---- valid-box count: first all-zero [2,3] box ----
    const float* gb = gt + (size_t)b * 384 + lane * 6;
    bool iszero = true;
#pragma unroll
    for (int k = 0; k < 6; ++k) iszero = iszero && (gb[k] == 0.0f);
    unsigned long long zmask = __ballot(iszero);
    const int c = zmask ? (__ffsll(zmask) - 1) : 64;

    __syncthreads();           // costL visible

    // ---- column -> scaled-int SSA vectors + on-grid check ----
    // ca[k] = cost[k][lane]*2^23, cb[k] = cost[k+32][lane]*2^23 (exact ints)
    i32x32 ca, cb;
    bool ongrid = true;
#pragma unroll
    for (int k = 0; k < 32; ++k) {
        const double h0 = (double)costL[(k     ) * 64 + lane] * 8388608.0;
        const double h1 = (double)costL[(k + 32) * 64 + lane] * 8388608.0;
        ongrid = ongrid && (h0 >= 0.0) && (h0 < 16777216.0) && (h0 == floor(h0))
                        && (h1 >= 0.0) && (h1 < 16777216.0) && (h1 == floor(h1));
        ca[k] = (int)h0; cb[k] = (int)h1;
    }
    const bool fast = (__ballot(ongrid) == ~0ULL);

    // opacity barrier: ca/cb are now opaque VGPR-resident SSA values; the
    // dynamic extracts below cannot be folded back into LDS loads.
    asm volatile("" : "+v"(ca), "+v"(cb));

    int path_r    = -1;        // path[lane]    (lane as col)
    int row4col_r = -1;        // row4col[lane] (lane as col)
    int col4row_r = -1;        // col4row[lane] (lane as row)

    if (fast) {
        // ---------------- int32-scaled solver, fully inlined ----------------
        int u_s = 0;           // u[lane] * 2^23   (lane as row)
        int v_s = 0;           // v[lane] * 2^23   (lane as col)

        for (int cur_row = 0; cur_row < c; ++cur_row) {
            int  minv_s    = 0x7FFFFFFF;
            bool remaining = true;
            unsigned long long SR = 0ULL;
            int  i       = cur_row;        // wave-uniform
            int  min_val = 0;
            int  sink    = -1;

            while (sink < 0) {
                SR |= 1ULL << i;
                const int u_i = __builtin_amdgcn_readlane(u_s, i);
                const int iu  = __builtin_amdgcn_readfirstlane(i);
                // uniform-index extractelement on SSA vectors -> v_movrels_b32
                const int cva = ca[iu & 31];
                const int cvb = cb[iu & 31];
                const int cv  = (iu < 32) ? cva : cvb;
                // exact integer arithmetic: order-insensitive
                const int r = (cv - v_s) + (min_val - u_i);
                const bool upd = remaining && (r < minv_s);
                minv_s = upd ? r : minv_s;
                path_r = upd ? i : path_r;

                const int key = remaining ? minv_s : 0x7FFFFFFF;
                int k = dpp_min_i32<0xB1>(key);     // xor 1
                k = dpp_min_i32<0x4E>(k);           // xor 2
                k = dpp_min_i32<0x141>(k);          // ROW_HALF_MIRROR (xor 4)
                k = dpp_min_i32<0x140>(k);          // ROW_MIRROR      (xor 8)
                const int m0 = __builtin_amdgcn_readlane(k, 0);
                const int m1 = __builtin_amdgcn_readlane(k, 16);
                const int m2 = __builtin_amdgcn_readlane(k, 32);
                const int m3 = __builtin_amdgcn_readlane(k, 48);
                const int ma = m0 < m1 ? m0 : m1;
                const int mb = m2 < m3 ? m2 : m3;
                const int gmin = ma < mb ? ma : mb;

                const unsigned long long eq = __ballot(key == gmin);
                const int jsel = __ffsll(eq) - 1;   // lowest-lane tie-break
                min_val   = gmin;
                remaining = remaining && (lane != jsel);
                const int rj = __builtin_amdgcn_readlane(row4col_r, jsel);
                if (rj < 0) sink = jsel; else i = rj;
            }

            // ---- dual updates (reference formulas, pre-augment col4row) ----
            {
                const bool scanned_row = (SR >> lane) & 1ULL;
                const int  gidx = col4row_r & 63;           // clamp -1 -> unused
                const int  mv_g = __shfl(minv_s, gidx, 64); // minv[col4row[lane]]
                if (lane == cur_row)       u_s += min_val;
                else if (scanned_row)      u_s += min_val - mv_g;
                if (!remaining)            v_s -= min_val - minv_s;
            }

            // ---- augment along alternating path (predicated lane writes) ----
            {
                int jj = sink;
                while (true) {
                    const int ii = __builtin_amdgcn_readlane(path_r, jj);
                    if (lane == jj) row4col_r = ii;
                    const int tmp = __builtin_amdgcn_readlane(col4row_r, ii);
                    if (lane == ii) col4row_r = jj;
                    jj = tmp;
                    if (ii == cur_row) break;
                }
            }
        }
    } else {
        run_lsap_f64(costL, lane, c, path_r, row4col_r, col4row_r);
    }

    // ---- ordering = concat(col4row[0:c], sorted unassigned columns) ----
    const bool assigned = (row4col_r >= 0);                 // lane as col
    const unsigned long long amask = __ballot(assigned);
    if (lane < c) ordL[lane] = col4row_r;                   // lane as row
    if (!assigned) {
        const unsigned long long below = (~amask) & ((1ULL << lane) - 1ULL);
        ordL[c + __popcll(below)] = lane;
    }
    __syncthreads();

    const int oc = ordL[lane];
    out[b * 64 + lane] = (float)oc;

    // ---- per-block loss partial: sum_r cost[r, ordering[r]] ----
    double p = (double)costL[lane * 64 + oc];
#pragma unroll
    for (int s = 1; s < 64; s <<= 1) p += __shfl_xor(p, s, 64);
    if (lane == 0) partial[b] = p;
}

__global__ __launch_bounds__(256)
void loss_reduce(const double* __restrict__ partial, float* __restrict__ out,
                 int B)
{
    const int t = threadIdx.x;
    __shared__ double sb[4];
    double p = 0.0;
    for (int idx = t; idx < B; idx += 256) p += partial[idx];
#pragma unroll
    for (int s = 1; s < 64; s <<= 1) p += __shfl_xor(p, s, 64);
    if ((t & 63) == 0) sb[t >> 6] = p;
    __syncthreads();
    if (t == 0)
        out[B * 64] = (float)((sb[0] + sb[1] + sb[2] + sb[3]) / (double)(B * 64));
}

extern "C" void kernel_launch(void* const* d_in, const int* in_sizes, int n_in,
                              void* d_out, int out_size, void* d_ws, size_t ws_size,
                              hipStream_t stream)
{
    const float* cost = (const float*)d_in[0];   // [B,64,64] f32
    const float* gt   = (const float*)d_in[1];   // [B,64,2,3] f32
    float* out        = (float*)d_out;           // [B*64] ordering + [1] loss
    double* partial   = (double*)d_ws;           // B doubles of scratch

    const int B = in_sizes[0] / 4096;            // 64*64 per problem

    lsap_solve<<<B, 64, 0, stream>>>(cost, gt, out, partial);
    loss_reduce<<<1, 256, 0, stream>>>(partial, out, B);
}

// Round 9
// 99.433 us; speedup vs baseline: 1.2918x; 1.0261x over previous
//
#include <hip/hip_runtime.h>

// 256 independent LSAP problems (scipy-trajectory-exact Jonker-Volgenant),
// one wave per problem, lane j owns column j and row j's dual state.
// FAST path (on-grid f32 inputs = exact multiples of 2^-23): solver runs in
// int32 scaled by 2^23 (exact order embedding -> identical trajectory).
// Cost column lives in two i32x32 SSA vectors (VReg_1024); per-scan read is
// extractelement with a readfirstlane'd (uniform) index -> v_movrels_b32.
// Wave-min reduction: fused v_min_i32_dpp chain (inline asm, explicit s_nop
// hazard slots). Fallback: verified f64/LDS path (round 3).

typedef int i32x32 __attribute__((ext_vector_type(32)));

union DU { double d; int i2[2]; };

__device__ inline double readlane_f64(double x, int l) {
    DU a; a.d = x;
    DU o;
    o.i2[0] = __builtin_amdgcn_readlane(a.i2[0], l);
    o.i2[1] = __builtin_amdgcn_readlane(a.i2[1], l);
    return o.d;
}

template <int CTRL>
__device__ inline double dpp_min_f64(double x) {
    DU a; a.d = x;
    DU b;
    b.i2[0] = __builtin_amdgcn_update_dpp(0, a.i2[0], CTRL, 0xF, 0xF, true);
    b.i2[1] = __builtin_amdgcn_update_dpp(0, a.i2[1], CTRL, 0xF, 0xF, true);
    return fmin(x, b.d);
}

// ---------------- fallback: verified round-3 f64 / LDS path ----------------
__device__ void run_lsap_f64(const float* __restrict__ costL, int lane, int c,
                             int& path_r, int& row4col_r, int& col4row_r)
{
    const double INF = __builtin_inf();
    double u_d = 0.0, v_d = 0.0;

    for (int cur_row = 0; cur_row < c; ++cur_row) {
        double minv_d    = INF;
        bool   remaining = true;
        unsigned long long SR = 0ULL;
        int    i       = cur_row;
        double min_val = 0.0;
        int    sink    = -1;

        while (sink < 0) {
            SR |= 1ULL << i;
            const double u_i = readlane_f64(u_d, i);
            const float  cf  = costL[i * 64 + lane];
            double r = min_val + (double)cf;   // numpy order, no FMA
            r = r - u_i;
            r = r - v_d;
            const bool upd = remaining && (r < minv_d);
            minv_d = upd ? r : minv_d;
            path_r = upd ? i : path_r;

            const double key = remaining ? minv_d : INF;
            double k = dpp_min_f64<0xB1>(key);
            k = dpp_min_f64<0x4E>(k);
            k = dpp_min_f64<0x141>(k);
            k = dpp_min_f64<0x140>(k);
            const double m0 = readlane_f64(k, 0);
            const double m1 = readlane_f64(k, 16);
            const double m2 = readlane_f64(k, 32);
            const double m3 = readlane_f64(k, 48);
            const double kmin = fmin(fmin(m0, m1), fmin(m2, m3));
            const unsigned long long eq = __ballot(key == kmin);
            const int jsel = __ffsll(eq) - 1;
            min_val = kmin;
            remaining = remaining && (lane != jsel);
            const int rj = __builtin_amdgcn_readlane(row4col_r, jsel);
            if (rj < 0) sink = jsel; else i = rj;
        }

        {
            const bool scanned_row = (SR >> lane) & 1ULL;
            const int  gidx = col4row_r & 63;
            const double mv_g = __shfl(minv_d, gidx, 64);
            if (lane == cur_row)       u_d += min_val;
            else if (scanned_row)      u_d += min_val - mv_g;
            if (!remaining)            v_d -= min_val - minv_d;
        }
        {
            int jj = sink;
            while (true) {
                const int ii = __builtin_amdgcn_readlane(path_r, jj);
                if (lane == jj) row4col_r = ii;
                const int tmp = __builtin_amdgcn_readlane(col4row_r, ii);
                if (lane == ii) col4row_r = jj;
                jj = tmp;
                if (ii == cur_row) break;
            }
        }
    }
}

__global__ __launch_bounds__(64)
void lsap_solve(const float* __restrict__ cost,
                const float* __restrict__ gt,
                float* __restrict__ out,
                double* __restrict__ partial)
{
    const int b    = blockIdx.x;
    const int lane = threadIdx.x;          // column index (and row index for u)

    __shared__ float costL[64 * 64];       // row-major [row][col]
    __shared__ int   ordL[64];

    // ---- stage cost matrix to LDS (coalesced float4) ----
    const float4* cb4 = (const float4*)(cost + (size_t)b * 4096);
    float4*       cl4 = (float4*)costL;
#pragma unroll
    for (int i = 0; i < 16; ++i)
        cl4[i * 64 + lane] = cb4[i * 64 + lane];

    // ---- valid-box count: first all-zero [2,3] box ----
    const float* gb = gt + (size_t)b * 384 + lane * 6;
    bool iszero = true;
#pragma unroll
    for (int k = 0; k < 6; ++k) iszero = iszero && (gb[k] == 0.0f);
    unsigned long long zmask = __ballot(iszero);
    const int c = zmask ? (__ffsll(zmask) - 1) : 64;

    __syncthreads();           // costL visible

    // ---- column -> scaled-int SSA vectors + on-grid check ----
    // ca[k] = cost[k][lane]*2^23, cb[k] = cost[k+32][lane]*2^23 (exact ints)
    i32x32 ca, cb;
    bool ongrid = true;
#pragma unroll
    for (int k = 0; k < 32; ++k) {
        const double h0 = (double)costL[(k     ) * 64 + lane] * 8388608.0;
        const double h1 = (double)costL[(k + 32) * 64 + lane] * 8388608.0;
        ongrid = ongrid && (h0 >= 0.0) && (h0 < 16777216.0) && (h0 == floor(h0))
                        && (h1 >= 0.0) && (h1 < 16777216.0) && (h1 == floor(h1));
        ca[k] = (int)h0; cb[k] = (int)h1;
    }
    const bool fast = (__ballot(ongrid) == ~0ULL);

    // opacity barrier: ca/cb are now opaque VGPR-resident SSA values; the
    // dynamic extracts below cannot be folded back into LDS loads.
    asm volatile("" : "+v"(ca), "+v"(cb));

    int path_r    = -1;        // path[lane]    (lane as col)
    int row4col_r = -1;        // row4col[lane] (lane as col)
    int col4row_r = -1;        // col4row[lane] (lane as row)

    if (fast) {
        // ---------------- int32-scaled solver, fully inlined ----------------
        int u_s = 0;           // u[lane] * 2^23   (lane as row)
        int v_s = 0;           // v[lane] * 2^23   (lane as col)

        for (int cur_row = 0; cur_row < c; ++cur_row) {
            int  minv_s    = 0x7FFFFFFF;
            bool remaining = true;
            unsigned long long SR = 0ULL;
            int  i       = cur_row;        // wave-uniform
            int  min_val = 0;
            int  sink    = -1;

            while (sink < 0) {
                SR |= 1ULL << i;
                const int u_i = __builtin_amdgcn_readlane(u_s, i);
                const int iu  = __builtin_amdgcn_readfirstlane(i);
                // uniform-index extractelement on SSA vectors -> v_movrels_b32
                const int cva = ca[iu & 31];
                const int cvb = cb[iu & 31];
                const int cv  = (iu < 32) ? cva : cvb;
                // exact integer arithmetic: order-insensitive
                const int r = (cv - v_s) + (min_val - u_i);
                const bool upd = remaining && (r < minv_s);
                minv_s = upd ? r : minv_s;
                path_r = upd ? i : path_r;

                const int key = remaining ? minv_s : 0x7FFFFFFF;
                // fused-DPP wave min -> gmin (SGPR). Same reduction network as
                // the verified round-5 u32 path: xor1,xor2,half_mirror,mirror,
                // then bcast15 (rows 1,3) and bcast31 (rows 2,3), min @ lane63.
                int kk = key;
                int gmin;
                asm volatile(
                    "s_nop 1\n\t"
                    "v_min_i32_dpp %0, %0, %0 quad_perm:[1,0,3,2] row_mask:0xf bank_mask:0xf\n\t"
                    "s_nop 1\n\t"
                    "v_min_i32_dpp %0, %0, %0 quad_perm:[2,3,0,1] row_mask:0xf bank_mask:0xf\n\t"
                    "s_nop 1\n\t"
                    "v_min_i32_dpp %0, %0, %0 row_half_mirror row_mask:0xf bank_mask:0xf\n\t"
                    "s_nop 1\n\t"
                    "v_min_i32_dpp %0, %0, %0 row_mirror row_mask:0xf bank_mask:0xf\n\t"
                    "s_nop 1\n\t"
                    "v_min_i32_dpp %0, %0, %0 row_bcast:15 row_mask:0xa bank_mask:0xf\n\t"
                    "s_nop 1\n\t"
                    "v_min_i32_dpp %0, %0, %0 row_bcast:31 row_mask:0xc bank_mask:0xf\n\t"
                    "s_nop 1\n\t"
                    "v_readlane_b32 %1, %0, 63"
                    : "+v"(kk), "=s"(gmin));

                const unsigned long long eq = __ballot(key == gmin);
                const int jsel = __ffsll(eq) - 1;   // lowest-lane tie-break
                min_val   = gmin;
                remaining = remaining && (lane != jsel);
                const int rj = __builtin_amdgcn_readlane(row4col_r, jsel);
                if (rj < 0) sink = jsel; else i = rj;
            }

            // ---- dual updates (reference formulas, pre-augment col4row) ----
            {
                const bool scanned_row = (SR >> lane) & 1ULL;
                const int  gidx = col4row_r & 63;           // clamp -1 -> unused
                const int  mv_g = __shfl(minv_s, gidx, 64); // minv[col4row[lane]]
                if (lane == cur_row)       u_s += min_val;
                else if (scanned_row)      u_s += min_val - mv_g;
                if (!remaining)            v_s -= min_val - minv_s;
            }

            // ---- augment along alternating path (predicated lane writes) ----
            {
                int jj = sink;
                while (true) {
                    const int ii = __builtin_amdgcn_readlane(path_r, jj);
                    if (lane == jj) row4col_r = ii;
                    const int tmp = __builtin_amdgcn_readlane(col4row_r, ii);
                    if (lane == ii) col4row_r = jj;
                    jj = tmp;
                    if (ii == cur_row) break;
                }
            }
        }
    } else {
        run_lsap_f64(costL, lane, c, path_r, row4col_r, col4row_r);
    }

    // ---- ordering = concat(col4row[0:c], sorted unassigned columns) ----
    const bool assigned = (row4col_r >= 0);                 // lane as col
    const unsigned long long amask = __ballot(assigned);
    if (lane < c) ordL[lane] = col4row_r;                   // lane as row
    if (!assigned) {
        const unsigned long long below = (~amask) & ((1ULL << lane) - 1ULL);
        ordL[c + __popcll(below)] = lane;
    }
    __syncthreads();

    const int oc = ordL[lane];
    out[b * 64 + lane] = (float)oc;

    // ---- per-block loss partial: sum_r cost[r, ordering[r]] ----
    double p = (double)costL[lane * 64 + oc];
#pragma unroll
    for (int s = 1; s < 64; s <<= 1) p += __shfl_xor(p, s, 64);
    if (lane == 0) partial[b] = p;
}

__global__ __launch_bounds__(256)
void loss_reduce(const double* __restrict__ partial, float* __restrict__ out,
                 int B)
{
    const int t = threadIdx.x;
    __shared__ double sb[4];
    double p = 0.0;
    for (int idx = t; idx < B; idx += 256) p += partial[idx];
#pragma unroll
    for (int s = 1; s < 64; s <<= 1) p += __shfl_xor(p, s, 64);
    if ((t & 63) == 0) sb[t >> 6] = p;
    __syncthreads();
    if (t == 0)
        out[B * 64] = (float)((sb[0] + sb[1] + sb[2] + sb[3]) / (double)(B * 64));
}

extern "C" void kernel_launch(void* const* d_in, const int* in_sizes, int n_in,
                              void* d_out, int out_size, void* d_ws, size_t ws_size,
                              hipStream_t stream)
{
    const float* cost = (const float*)d_in[0];   // [B,64,64] f32
    const float* gt   = (const float*)d_in[1];   // [B,64,2,3] f32
    float* out        = (float*)d_out;           // [B*64] ordering + [1] loss
    double* partial   = (double*)d_ws;           // B doubles of scratch

    const int B = in_sizes[0] / 4096;            // 64*64 per problem

    lsap_solve<<<B, 64, 0, stream>>>(cost, gt, out, partial);
    loss_reduce<<<1, 256, 0, stream>>>(partial, out, B);
}